// Round 9
// baseline (307.078 us; speedup 1.0000x reference)
//
#include <hip/hip_runtime.h>
#include <hip/hip_bf16.h>

#define N_NODES 50000
#define N_EDGES 1600000
#define NREL    16
#define DIM     64
#define KDIM    1024          // NREL * DIM

#define NBKT    391           // ceil(50000/128) buckets of 128 dst nodes
#define P1_CHUNK 2048
#define P1_GRID  782          // ceil(1.6M/2048)

typedef __attribute__((ext_vector_type(8))) short short8;
typedef __attribute__((ext_vector_type(4))) float float4v;

template<int IS_F32>
__device__ __forceinline__ float ldx(const void* p, size_t i) {
    if (IS_F32) {
        return ((const float*)p)[i];
    } else {
        unsigned short u = ((const unsigned short*)p)[i];
        return __uint_as_float(((unsigned)u) << 16);
    }
}

__device__ __forceinline__ float bfbits2f(unsigned short u) {
    return __uint_as_float(((unsigned)u) << 16);
}

__device__ __forceinline__ unsigned short f2bfbits(float v) {
    __hip_bfloat16 b = __float2bfloat16(v);
    unsigned short us; __builtin_memcpy(&us, &b, 2);
    return us;
}

// ---------------------------------------------------------------------------
// Dtype detector (proven): flag=1 if f32 dataset, 0 if bf16.
// ---------------------------------------------------------------------------
__global__ __launch_bounds__(1024) void k_detect(
    const float* __restrict__ norm_f, int* __restrict__ flag)
{
    __shared__ int sbad;
    if (threadIdx.x == 0) sbad = 0;
    __syncthreads();
    float v = norm_f[threadIdx.x];
    int bad = (v != v || fabsf(v) > 1e3f) ? 1 : 0;
    if (bad) atomicOr(&sbad, 1);
    __syncthreads();
    if (threadIdx.x == 0) *flag = sbad ? 0 : 1;
}

// ---------------------------------------------------------------------------
// Bucket histogram (proven, atomic-free at global scope).
// ---------------------------------------------------------------------------
__global__ __launch_bounds__(256) void k_bhist(
    const int* __restrict__ dst, int* __restrict__ H)
{
    __shared__ int hist[NBKT];
    for (int i = threadIdx.x; i < NBKT; i += 256) hist[i] = 0;
    __syncthreads();
    const int e0 = blockIdx.x * P1_CHUNK;
    for (int i = threadIdx.x; i < P1_CHUNK; i += 256) {
        int e = e0 + i;
        if (e < N_EDGES) atomicAdd(&hist[dst[e] >> 7], 1);
    }
    __syncthreads();
    for (int b = threadIdx.x; b < NBKT; b += 256)
        H[blockIdx.x * NBKT + b] = hist[b];
}

__global__ __launch_bounds__(256) void k_bscan1(
    const int* __restrict__ H, int* __restrict__ OT, int* __restrict__ tot)
{
    __shared__ int col[P1_GRID];
    const int b = blockIdx.x;
    for (int i = threadIdx.x; i < P1_GRID; i += 256)
        col[i] = H[i * NBKT + b];
    __syncthreads();
    if (threadIdx.x < 64) {
        const int lane = threadIdx.x;
        int carry = 0;
        for (int chunk = 0; chunk < (P1_GRID + 63) / 64; ++chunk) {
            int i = chunk * 64 + lane;
            int c = (i < P1_GRID) ? col[i] : 0;
            int incl = c;
#pragma unroll
            for (int off = 1; off < 64; off <<= 1) {
                int t = __shfl_up(incl, off, 64);
                if (lane >= off) incl += t;
            }
            if (i < P1_GRID) col[i] = carry + incl - c;
            carry += __shfl(incl, 63, 64);
        }
        if (lane == 0) tot[b] = carry;
    }
    __syncthreads();
    for (int i = threadIdx.x; i < P1_GRID; i += 256)
        OT[(size_t)b * P1_GRID + i] = col[i];
}

__global__ __launch_bounds__(64) void k_bscan2(
    const int* __restrict__ tot, int* __restrict__ base)
{
    const int lane = threadIdx.x;
    int carry = 0;
    for (int chunk = 0; chunk < (NBKT + 63) / 64; ++chunk) {
        int i = chunk * 64 + lane;
        int c = (i < NBKT) ? tot[i] : 0;
        int incl = c;
#pragma unroll
        for (int off = 1; off < 64; off <<= 1) {
            int t = __shfl_up(incl, off, 64);
            if (lane >= off) incl += t;
        }
        if (i < NBKT) base[i] = carry + incl - c;
        carry += __shfl(incl, 63, 64);
    }
    if (lane == 0) base[NBKT] = carry;   // == N_EDGES
}

// ---------------------------------------------------------------------------
// P1 (proven): multisplit into bucket runs, deterministic reservation.
// rec: [7:0]=dst&127, [23:8]=src, [27:24]=rel, [47:32]=norm bf16.
// ---------------------------------------------------------------------------
template<int IS_F32>
__device__ __forceinline__ void p1_body(
    const int* __restrict__ src, const int* __restrict__ dst,
    const int* __restrict__ rel, const void* __restrict__ norm_raw,
    const int* __restrict__ base, const int* __restrict__ OT,
    unsigned long long* __restrict__ R, int* curs)
{
    const int blk = blockIdx.x;
    for (int b = threadIdx.x; b < NBKT; b += 256)
        curs[b] = base[b] + OT[(size_t)b * P1_GRID + blk];
    __syncthreads();
    const int e0 = blk * P1_CHUNK;
    for (int i = threadIdx.x; i < P1_CHUNK; i += 256) {
        int e = e0 + i;
        if (e >= N_EDGES) continue;
        int d = dst[e];
        int pos = atomicAdd(&curs[d >> 7], 1);
        unsigned short nb = f2bfbits(ldx<IS_F32>(norm_raw, e));
        unsigned long long rec =
              (unsigned long long)(d & 127)
            | ((unsigned long long)(unsigned)src[e] << 8)
            | ((unsigned long long)(unsigned)rel[e] << 24)
            | ((unsigned long long)nb << 32);
        R[pos] = rec;
    }
}

__global__ __launch_bounds__(256) void k_p1(
    const int* __restrict__ src, const int* __restrict__ dst,
    const int* __restrict__ rel, const void* __restrict__ norm_raw,
    const int* __restrict__ base, const int* __restrict__ OT,
    unsigned long long* __restrict__ R, const int* __restrict__ flag)
{
    __shared__ int curs[NBKT];
    if (*flag) p1_body<1>(src, dst, rel, norm_raw, base, OT, R, curs);
    else       p1_body<0>(src, dst, rel, norm_raw, base, OT, R, curs);
}

// ---------------------------------------------------------------------------
// P2 (proven): per-bucket exact CSR placement + A[] emission.
// ---------------------------------------------------------------------------
__global__ __launch_bounds__(256) void k_p2(
    const int* __restrict__ base,
    const unsigned long long* __restrict__ R,
    unsigned* __restrict__ packed,
    unsigned short* __restrict__ normS,
    int* __restrict__ A)
{
    __shared__ int cnt[128];
    __shared__ int Aex[128];
    __shared__ int curs[128];
    __shared__ int tot0s;
    const int tid = threadIdx.x;
    if (tid < 128) { cnt[tid] = 0; curs[tid] = 0; }
    __syncthreads();

    const int b  = blockIdx.x;
    const int n0 = b << 7;
    const int nn = min(128, N_NODES - n0);
    const int c0 = base[b], c1 = base[b + 1];

    for (int i = c0 + tid; i < c1; i += 256)
        atomicAdd(&cnt[(int)(R[i] & 127)], 1);
    __syncthreads();

    if (tid < 64) {
        int c = cnt[tid], incl = c;
#pragma unroll
        for (int off = 1; off < 64; off <<= 1) {
            int t = __shfl_up(incl, off, 64);
            if (tid >= off) incl += t;
        }
        Aex[tid] = c0 + incl - c;
        if (tid == 63) tot0s = incl;
    }
    __syncthreads();
    if (tid >= 64 && tid < 128) {
        int lane = tid - 64;
        int c = cnt[tid], incl = c;
#pragma unroll
        for (int off = 1; off < 64; off <<= 1) {
            int t = __shfl_up(incl, off, 64);
            if (lane >= off) incl += t;
        }
        Aex[tid] = c0 + tot0s + incl - c;
    }
    __syncthreads();

    if (tid < nn) A[n0 + tid] = Aex[tid];
    if (b == NBKT - 1 && tid == 0) A[N_NODES] = c1;

    for (int i = c0 + tid; i < c1; i += 256) {
        unsigned long long rec = R[i];
        int nl = (int)(rec & 127);
        int pos = Aex[nl] + atomicAdd(&curs[nl], 1);
        packed[pos] = (unsigned)((rec >> 8) & 0xFFFFFFu);
        normS[pos]  = (unsigned short)(rec >> 32);
    }
}

// ---------------------------------------------------------------------------
// K_GATHER: g[v][r*64+d] = sum_{e->v, rel=r} norm_e * h[src_e][d].
// One wave per dst node, lane = d. h is 6.4 MB -> L2/L3-resident gather.
// 16 scalar accumulators, wave-uniform switch on rel (scalar branches).
// ---------------------------------------------------------------------------
#define ACC_EDGE(RV, HV, NV)                                          \
    switch (RV) {                                                     \
    case 0:  acc0  = fmaf(HV, NV, acc0);  break;                      \
    case 1:  acc1  = fmaf(HV, NV, acc1);  break;                      \
    case 2:  acc2  = fmaf(HV, NV, acc2);  break;                      \
    case 3:  acc3  = fmaf(HV, NV, acc3);  break;                      \
    case 4:  acc4  = fmaf(HV, NV, acc4);  break;                      \
    case 5:  acc5  = fmaf(HV, NV, acc5);  break;                      \
    case 6:  acc6  = fmaf(HV, NV, acc6);  break;                      \
    case 7:  acc7  = fmaf(HV, NV, acc7);  break;                      \
    case 8:  acc8  = fmaf(HV, NV, acc8);  break;                      \
    case 9:  acc9  = fmaf(HV, NV, acc9);  break;                      \
    case 10: acc10 = fmaf(HV, NV, acc10); break;                      \
    case 11: acc11 = fmaf(HV, NV, acc11); break;                      \
    case 12: acc12 = fmaf(HV, NV, acc12); break;                      \
    case 13: acc13 = fmaf(HV, NV, acc13); break;                      \
    case 14: acc14 = fmaf(HV, NV, acc14); break;                      \
    default: acc15 = fmaf(HV, NV, acc15); break;                      \
    }

template<int IS_F32>
__device__ __forceinline__ void gather_body(
    const unsigned* __restrict__ packed,
    const unsigned short* __restrict__ normS,
    const void* __restrict__ h_raw,
    const int* __restrict__ A,
    __hip_bfloat16* __restrict__ g)
{
    const int lane = threadIdx.x & 63;
    const int v = blockIdx.x * 4 + (threadIdx.x >> 6);
    if (v >= N_NODES) return;

    const int start = __builtin_amdgcn_readfirstlane(A[v]);
    const int end   = __builtin_amdgcn_readfirstlane(A[v + 1]);

    float acc0 = 0.f, acc1 = 0.f, acc2 = 0.f, acc3 = 0.f;
    float acc4 = 0.f, acc5 = 0.f, acc6 = 0.f, acc7 = 0.f;
    float acc8 = 0.f, acc9 = 0.f, acc10 = 0.f, acc11 = 0.f;
    float acc12 = 0.f, acc13 = 0.f, acc14 = 0.f, acc15 = 0.f;

    int i = start;
    for (; i + 4 <= end; i += 4) {
        unsigned u0 = packed[i],     u1 = packed[i + 1];
        unsigned u2 = packed[i + 2], u3 = packed[i + 3];
        float h0 = ldx<IS_F32>(h_raw, (size_t)(u0 & 0xFFFFu) * DIM + lane);
        float h1 = ldx<IS_F32>(h_raw, (size_t)(u1 & 0xFFFFu) * DIM + lane);
        float h2 = ldx<IS_F32>(h_raw, (size_t)(u2 & 0xFFFFu) * DIM + lane);
        float h3 = ldx<IS_F32>(h_raw, (size_t)(u3 & 0xFFFFu) * DIM + lane);
        float n0 = bfbits2f(normS[i]),     n1 = bfbits2f(normS[i + 1]);
        float n2 = bfbits2f(normS[i + 2]), n3 = bfbits2f(normS[i + 3]);
        int r0 = __builtin_amdgcn_readfirstlane((int)(u0 >> 16));
        int r1 = __builtin_amdgcn_readfirstlane((int)(u1 >> 16));
        int r2 = __builtin_amdgcn_readfirstlane((int)(u2 >> 16));
        int r3 = __builtin_amdgcn_readfirstlane((int)(u3 >> 16));
        ACC_EDGE(r0, h0, n0)
        ACC_EDGE(r1, h1, n1)
        ACC_EDGE(r2, h2, n2)
        ACC_EDGE(r3, h3, n3)
    }
    for (; i < end; ++i) {
        unsigned u0 = packed[i];
        float h0 = ldx<IS_F32>(h_raw, (size_t)(u0 & 0xFFFFu) * DIM + lane);
        float n0 = bfbits2f(normS[i]);
        int r0 = __builtin_amdgcn_readfirstlane((int)(u0 >> 16));
        ACC_EDGE(r0, h0, n0)
    }

    unsigned short* gp = (unsigned short*)g + (size_t)v * KDIM + lane;
    gp[0 * 64]  = f2bfbits(acc0);  gp[1 * 64]  = f2bfbits(acc1);
    gp[2 * 64]  = f2bfbits(acc2);  gp[3 * 64]  = f2bfbits(acc3);
    gp[4 * 64]  = f2bfbits(acc4);  gp[5 * 64]  = f2bfbits(acc5);
    gp[6 * 64]  = f2bfbits(acc6);  gp[7 * 64]  = f2bfbits(acc7);
    gp[8 * 64]  = f2bfbits(acc8);  gp[9 * 64]  = f2bfbits(acc9);
    gp[10 * 64] = f2bfbits(acc10); gp[11 * 64] = f2bfbits(acc11);
    gp[12 * 64] = f2bfbits(acc12); gp[13 * 64] = f2bfbits(acc13);
    gp[14 * 64] = f2bfbits(acc14); gp[15 * 64] = f2bfbits(acc15);
}

__global__ __launch_bounds__(256) void k_gather(
    const unsigned* __restrict__ packed,
    const unsigned short* __restrict__ normS,
    const void* __restrict__ h_raw,
    const int* __restrict__ A,
    __hip_bfloat16* __restrict__ g,
    const int* __restrict__ flag)
{
    if (*flag) gather_body<1>(packed, normS, h_raw, A, g);
    else       gather_body<0>(packed, normS, h_raw, A, g);
}

// ---------------------------------------------------------------------------
// K2 (MFMA GEMM): out[v][o] = relu( sum_k g[v][k] * Wf[k][o] ), k = r*64+d,
// Wf[k][o] = W[k>>6][k&63][o]. Node tile 256/block, K chunked 4x256, W chunk
// swizzled to LDS in the proven B-frag order (stride 40, ds_read_b128).
// ---------------------------------------------------------------------------
template<int IS_F32>
__device__ __forceinline__ void k2_body(
    const __hip_bfloat16* __restrict__ g,
    const void* __restrict__ w_raw,
    void* __restrict__ out,
    short* Wl)
{
    const int lane = threadIdx.x & 63;
    const int wave = threadIdx.x >> 6;
    const int n15  = lane & 15;
    const int quad = lane >> 4;
    const int nblk = blockIdx.x * 256;

    float4v acc[4][4];
#pragma unroll
    for (int ng = 0; ng < 4; ++ng)
#pragma unroll
        for (int t = 0; t < 4; ++t)
            acc[ng][t] = (float4v){0.f, 0.f, 0.f, 0.f};

    for (int kc = 0; kc < 4; ++kc) {
        __syncthreads();
        for (int idx = threadIdx.x; idx < 16384; idx += 256) {
            int o = idx & 63, kl = idx >> 6;                  // kl in [0,256)
            int s = kl >> 5, q = (kl >> 3) & 3, j = kl & 7;
            int k = kc * 256 + kl;
            float wv = ldx<IS_F32>(w_raw, (size_t)k * 64 + o);
            Wl[(s * 64 + o) * 40 + q * 8 + j] = (short)f2bfbits(wv);
        }
        __syncthreads();

#pragma unroll
        for (int ng = 0; ng < 4; ++ng) {
            const int node0 = nblk + ng * 64 + wave * 16;
            if (node0 >= N_NODES) continue;  // 50000 % 16 == 0

            const uint4* gp = (const uint4*)((const unsigned short*)g
                + (size_t)(node0 + n15) * KDIM + kc * 256 + quad * 8);
            short8 af[8];
#pragma unroll
            for (int s = 0; s < 8; ++s) {
                uint4 vv = gp[s * 4];   // s*32 shorts = 4 uint4
                __builtin_memcpy(&af[s], &vv, 16);
            }
#pragma unroll
            for (int s = 0; s < 8; ++s) {
#pragma unroll
                for (int t = 0; t < 4; ++t) {
                    const short8* bf = (const short8*)&Wl[(s * 64 + t * 16 + n15) * 40 + quad * 8];
                    acc[ng][t] = __builtin_amdgcn_mfma_f32_16x16x32_bf16(af[s], *bf, acc[ng][t], 0, 0, 0);
                }
            }
        }
    }

#pragma unroll
    for (int ng = 0; ng < 4; ++ng) {
        const int node0 = nblk + ng * 64 + wave * 16;
        if (node0 >= N_NODES) continue;
#pragma unroll
        for (int t = 0; t < 4; ++t) {
#pragma unroll
            for (int i = 0; i < 4; ++i) {
                int node = node0 + quad * 4 + i;
                float r = fmaxf(acc[ng][t][i], 0.f);
                size_t ob = (size_t)node * DIM + t * 16 + n15;
                if (IS_F32) ((float*)out)[ob] = r;
                else        ((unsigned short*)out)[ob] = f2bfbits(r);
            }
        }
    }
}

__global__ __launch_bounds__(256) void k2_mfma(
    const __hip_bfloat16* __restrict__ g,
    const void* __restrict__ w_raw,
    void* __restrict__ out,
    const int* __restrict__ flag)
{
    __shared__ short Wl[512 * 40];   // 40 KB
    if (*flag) k2_body<1>(g, w_raw, out, Wl);
    else       k2_body<0>(g, w_raw, out, Wl);
}

// ---------------------------------------------------------------------------
extern "C" void kernel_launch(void* const* d_in, const int* in_sizes, int n_in,
                              void* d_out, int out_size, void* d_ws, size_t ws_size,
                              hipStream_t stream)
{
    const void* h      = d_in[0];
    const void* weight = d_in[1];
    const void* norm   = d_in[2];
    const int* src = (const int*)d_in[3];
    const int* dst = (const int*)d_in[4];
    const int* rel = (const int*)d_in[5];

    // ws: flag(256) | A[50001] | base | tot | H | OT | packed u32[E]
    //     | normS u16[E] | g bf16[N*1024]  (R u64[E] aliases g; consumed by
    //     k_p2 before k_gather writes g — stream order)
    char* w = (char*)d_ws;
    int*   flag = (int*)w;                      w += 256;
    int*   A    = (int*)w;                      w += 200192;
    int*   base = (int*)w;                      w += 2048;
    int*   tot  = (int*)w;                      w += 2048;
    int*   H    = (int*)w;                      w += (size_t)P1_GRID * NBKT * 4;
    int*   OT   = (int*)w;                      w += (size_t)NBKT * P1_GRID * 4;
    unsigned* packed = (unsigned*)w;            w += (size_t)N_EDGES * 4;
    unsigned short* normS = (unsigned short*)w; w += (size_t)N_EDGES * 2;
    __hip_bfloat16* g = (__hip_bfloat16*)w;
    unsigned long long* R = (unsigned long long*)g;

    k_detect<<<1, 1024, 0, stream>>>((const float*)norm, flag);

    k_bhist<<<P1_GRID, 256, 0, stream>>>(dst, H);
    k_bscan1<<<NBKT, 256, 0, stream>>>(H, OT, tot);
    k_bscan2<<<1, 64, 0, stream>>>(tot, base);

    k_p1<<<P1_GRID, 256, 0, stream>>>(src, dst, rel, norm, base, OT, R, flag);
    k_p2<<<NBKT, 256, 0, stream>>>(base, R, packed, normS, A);

    k_gather<<<12500, 256, 0, stream>>>(packed, normS, h, A, g, flag);

    k2_mfma<<<(N_NODES + 255) / 256, 256, 0, stream>>>(g, weight, d_out, flag);
}

// Round 10
// 292.341 us; speedup vs baseline: 1.0504x; 1.0504x over previous
//
#include <hip/hip_runtime.h>
#include <hip/hip_bf16.h>

#define N_NODES 50000
#define N_EDGES 1600000
#define NREL    16
#define DIM     64
#define KDIM    1024          // NREL * DIM

#define NBKT    391           // ceil(50000/128) buckets of 128 dst nodes
#define P1_CHUNK 2048
#define P1_GRID  782          // ceil(1.6M/2048)

typedef __attribute__((ext_vector_type(8))) short short8;
typedef __attribute__((ext_vector_type(4))) float float4v;

template<int IS_F32>
__device__ __forceinline__ float ldx(const void* p, size_t i) {
    if (IS_F32) {
        return ((const float*)p)[i];
    } else {
        unsigned short u = ((const unsigned short*)p)[i];
        return __uint_as_float(((unsigned)u) << 16);
    }
}

__device__ __forceinline__ float bfbits2f(unsigned short u) {
    return __uint_as_float(((unsigned)u) << 16);
}

__device__ __forceinline__ unsigned short f2bfbits(float v) {
    __hip_bfloat16 b = __float2bfloat16(v);
    unsigned short us; __builtin_memcpy(&us, &b, 2);
    return us;
}

// ---------------------------------------------------------------------------
// Dtype detector (proven): flag=1 if f32 dataset, 0 if bf16.
// ---------------------------------------------------------------------------
__global__ __launch_bounds__(1024) void k_detect(
    const float* __restrict__ norm_f, int* __restrict__ flag)
{
    __shared__ int sbad;
    if (threadIdx.x == 0) sbad = 0;
    __syncthreads();
    float v = norm_f[threadIdx.x];
    int bad = (v != v || fabsf(v) > 1e3f) ? 1 : 0;
    if (bad) atomicOr(&sbad, 1);
    __syncthreads();
    if (threadIdx.x == 0) *flag = sbad ? 0 : 1;
}

// ---------------------------------------------------------------------------
// Bucket histogram (proven, atomic-free at global scope).
// ---------------------------------------------------------------------------
__global__ __launch_bounds__(256) void k_bhist(
    const int* __restrict__ dst, int* __restrict__ H)
{
    __shared__ int hist[NBKT];
    for (int i = threadIdx.x; i < NBKT; i += 256) hist[i] = 0;
    __syncthreads();
    const int e0 = blockIdx.x * P1_CHUNK;
    for (int i = threadIdx.x; i < P1_CHUNK; i += 256) {
        int e = e0 + i;
        if (e < N_EDGES) atomicAdd(&hist[dst[e] >> 7], 1);
    }
    __syncthreads();
    for (int b = threadIdx.x; b < NBKT; b += 256)
        H[blockIdx.x * NBKT + b] = hist[b];
}

__global__ __launch_bounds__(256) void k_bscan1(
    const int* __restrict__ H, int* __restrict__ OT, int* __restrict__ tot)
{
    __shared__ int col[P1_GRID];
    const int b = blockIdx.x;
    for (int i = threadIdx.x; i < P1_GRID; i += 256)
        col[i] = H[i * NBKT + b];
    __syncthreads();
    if (threadIdx.x < 64) {
        const int lane = threadIdx.x;
        int carry = 0;
        for (int chunk = 0; chunk < (P1_GRID + 63) / 64; ++chunk) {
            int i = chunk * 64 + lane;
            int c = (i < P1_GRID) ? col[i] : 0;
            int incl = c;
#pragma unroll
            for (int off = 1; off < 64; off <<= 1) {
                int t = __shfl_up(incl, off, 64);
                if (lane >= off) incl += t;
            }
            if (i < P1_GRID) col[i] = carry + incl - c;
            carry += __shfl(incl, 63, 64);
        }
        if (lane == 0) tot[b] = carry;
    }
    __syncthreads();
    for (int i = threadIdx.x; i < P1_GRID; i += 256)
        OT[(size_t)b * P1_GRID + i] = col[i];
}

__global__ __launch_bounds__(64) void k_bscan2(
    const int* __restrict__ tot, int* __restrict__ base)
{
    const int lane = threadIdx.x;
    int carry = 0;
    for (int chunk = 0; chunk < (NBKT + 63) / 64; ++chunk) {
        int i = chunk * 64 + lane;
        int c = (i < NBKT) ? tot[i] : 0;
        int incl = c;
#pragma unroll
        for (int off = 1; off < 64; off <<= 1) {
            int t = __shfl_up(incl, off, 64);
            if (lane >= off) incl += t;
        }
        if (i < NBKT) base[i] = carry + incl - c;
        carry += __shfl(incl, 63, 64);
    }
    if (lane == 0) base[NBKT] = carry;   // == N_EDGES
}

// ---------------------------------------------------------------------------
// P1 (proven): multisplit into bucket runs, deterministic reservation.
// rec: [7:0]=dst&127, [23:8]=src, [27:24]=rel, [47:32]=norm bf16.
// ---------------------------------------------------------------------------
template<int IS_F32>
__device__ __forceinline__ void p1_body(
    const int* __restrict__ src, const int* __restrict__ dst,
    const int* __restrict__ rel, const void* __restrict__ norm_raw,
    const int* __restrict__ base, const int* __restrict__ OT,
    unsigned long long* __restrict__ R, int* curs)
{
    const int blk = blockIdx.x;
    for (int b = threadIdx.x; b < NBKT; b += 256)
        curs[b] = base[b] + OT[(size_t)b * P1_GRID + blk];
    __syncthreads();
    const int e0 = blk * P1_CHUNK;
    for (int i = threadIdx.x; i < P1_CHUNK; i += 256) {
        int e = e0 + i;
        if (e >= N_EDGES) continue;
        int d = dst[e];
        int pos = atomicAdd(&curs[d >> 7], 1);
        unsigned short nb = f2bfbits(ldx<IS_F32>(norm_raw, e));
        unsigned long long rec =
              (unsigned long long)(d & 127)
            | ((unsigned long long)(unsigned)src[e] << 8)
            | ((unsigned long long)(unsigned)rel[e] << 24)
            | ((unsigned long long)nb << 32);
        R[pos] = rec;
    }
}

__global__ __launch_bounds__(256) void k_p1(
    const int* __restrict__ src, const int* __restrict__ dst,
    const int* __restrict__ rel, const void* __restrict__ norm_raw,
    const int* __restrict__ base, const int* __restrict__ OT,
    unsigned long long* __restrict__ R, const int* __restrict__ flag)
{
    __shared__ int curs[NBKT];
    if (*flag) p1_body<1>(src, dst, rel, norm_raw, base, OT, R, curs);
    else       p1_body<0>(src, dst, rel, norm_raw, base, OT, R, curs);
}

// ---------------------------------------------------------------------------
// P2: one block per bucket; NOW sorts by (node, rel): 2048 LDS counters
// (key = local_node*16 + rel), scan, exact placement. Emits A[] per node.
// ---------------------------------------------------------------------------
__global__ __launch_bounds__(256) void k_p2(
    const int* __restrict__ base,
    const unsigned long long* __restrict__ R,
    unsigned* __restrict__ packed,
    unsigned short* __restrict__ normS,
    int* __restrict__ A)
{
    __shared__ int cnt[2048];     // becomes exclusive offsets, then cursors
    __shared__ int tsum[256];
    __shared__ int wsum[4];
    const int tid = threadIdx.x;
    for (int i = tid; i < 2048; i += 256) cnt[i] = 0;
    __syncthreads();

    const int b  = blockIdx.x;
    const int n0 = b << 7;
    const int nn = min(128, N_NODES - n0);
    const int c0 = base[b], c1 = base[b + 1];

    // count (node, rel) pairs
    for (int i = c0 + tid; i < c1; i += 256) {
        unsigned long long rec = R[i];
        int key = ((int)(rec & 127) << 4) | ((int)(rec >> 24) & 15);
        atomicAdd(&cnt[key], 1);
    }
    __syncthreads();

    // exclusive scan of cnt[2048]: thread owns 8 consecutive keys
    int c[8]; int s = 0;
#pragma unroll
    for (int m = 0; m < 8; ++m) { c[m] = cnt[tid * 8 + m]; s += c[m]; }
    tsum[tid] = s;
    __syncthreads();
    {
        const int wave = tid >> 6, lane = tid & 63;
        int x = tsum[tid], incl = x;
#pragma unroll
        for (int off = 1; off < 64; off <<= 1) {
            int t = __shfl_up(incl, off, 64);
            if (lane >= off) incl += t;
        }
        if (lane == 63) wsum[wave] = incl;
        __syncthreads();
        if (tid == 0) {
            int r = 0;
#pragma unroll
            for (int wv = 0; wv < 4; ++wv) { int t = wsum[wv]; wsum[wv] = r; r += t; }
        }
        __syncthreads();
        int run = c0 + wsum[wave] + (incl - x);
#pragma unroll
        for (int m = 0; m < 8; ++m) { cnt[tid * 8 + m] = run; run += c[m]; }
    }
    __syncthreads();

    if (tid < nn) A[n0 + tid] = cnt[tid << 4];   // offset of (node, rel=0)
    if (b == NBKT - 1 && tid == 0) A[N_NODES] = c1;

    // place, cursors = cnt in place
    for (int i = c0 + tid; i < c1; i += 256) {
        unsigned long long rec = R[i];
        int key = ((int)(rec & 127) << 4) | ((int)(rec >> 24) & 15);
        int pos = atomicAdd(&cnt[key], 1);
        packed[pos] = (unsigned)((rec >> 8) & 0xFFFFFFu);
        normS[pos]  = (unsigned short)(rec >> 32);
    }
}

// ---------------------------------------------------------------------------
// K_GATHER: g[v][r*64+d] = sum_{e->v, rel=r} norm_e * h[src_e][d].
// Edges sorted by (v, rel): single running accumulator, flush on rel change,
// zero-fill skipped rels. 4-deep h-load pipeline. NT stores for g (don't
// pollute L3 — keep h resident).
// ---------------------------------------------------------------------------
template<int IS_F32>
__device__ __forceinline__ void gather_flush(
    unsigned short* gp, int& cur, float& acc, int r_new)
{
    if (cur >= 0)
        __builtin_nontemporal_store(f2bfbits(acc), gp + cur * 64);
    for (int x = cur + 1; x < r_new; ++x)
        __builtin_nontemporal_store((unsigned short)0, gp + x * 64);
    cur = r_new;
    acc = 0.f;
}

template<int IS_F32>
__device__ __forceinline__ void gather_body(
    const unsigned* __restrict__ packed,
    const unsigned short* __restrict__ normS,
    const void* __restrict__ h_raw,
    const int* __restrict__ A,
    __hip_bfloat16* __restrict__ g)
{
    const int lane = threadIdx.x & 63;
    const int v = blockIdx.x * 4 + (threadIdx.x >> 6);
    if (v >= N_NODES) return;

    const int start = __builtin_amdgcn_readfirstlane(A[v]);
    const int end   = __builtin_amdgcn_readfirstlane(A[v + 1]);

    unsigned short* gp = (unsigned short*)g + (size_t)v * KDIM + lane;
    float acc = 0.f;
    int cur = -1;

    int i = start;
    for (; i + 4 <= end; i += 4) {
        unsigned u0 = __builtin_nontemporal_load(packed + i);
        unsigned u1 = __builtin_nontemporal_load(packed + i + 1);
        unsigned u2 = __builtin_nontemporal_load(packed + i + 2);
        unsigned u3 = __builtin_nontemporal_load(packed + i + 3);
        float h0 = ldx<IS_F32>(h_raw, (size_t)(u0 & 0xFFFFu) * DIM + lane);
        float h1 = ldx<IS_F32>(h_raw, (size_t)(u1 & 0xFFFFu) * DIM + lane);
        float h2 = ldx<IS_F32>(h_raw, (size_t)(u2 & 0xFFFFu) * DIM + lane);
        float h3 = ldx<IS_F32>(h_raw, (size_t)(u3 & 0xFFFFu) * DIM + lane);
        float n0 = bfbits2f(__builtin_nontemporal_load(normS + i));
        float n1 = bfbits2f(__builtin_nontemporal_load(normS + i + 1));
        float n2 = bfbits2f(__builtin_nontemporal_load(normS + i + 2));
        float n3 = bfbits2f(__builtin_nontemporal_load(normS + i + 3));
        int r0 = __builtin_amdgcn_readfirstlane((int)(u0 >> 16));
        int r1 = __builtin_amdgcn_readfirstlane((int)(u1 >> 16));
        int r2 = __builtin_amdgcn_readfirstlane((int)(u2 >> 16));
        int r3 = __builtin_amdgcn_readfirstlane((int)(u3 >> 16));
        if (r0 != cur) gather_flush<IS_F32>(gp, cur, acc, r0);
        acc = fmaf(h0, n0, acc);
        if (r1 != cur) gather_flush<IS_F32>(gp, cur, acc, r1);
        acc = fmaf(h1, n1, acc);
        if (r2 != cur) gather_flush<IS_F32>(gp, cur, acc, r2);
        acc = fmaf(h2, n2, acc);
        if (r3 != cur) gather_flush<IS_F32>(gp, cur, acc, r3);
        acc = fmaf(h3, n3, acc);
    }
    for (; i < end; ++i) {
        unsigned u0 = __builtin_nontemporal_load(packed + i);
        float h0 = ldx<IS_F32>(h_raw, (size_t)(u0 & 0xFFFFu) * DIM + lane);
        float n0 = bfbits2f(__builtin_nontemporal_load(normS + i));
        int r0 = __builtin_amdgcn_readfirstlane((int)(u0 >> 16));
        if (r0 != cur) gather_flush<IS_F32>(gp, cur, acc, r0);
        acc = fmaf(h0, n0, acc);
    }
    // final flush + zero-fill remaining rels (handles empty nodes: cur=-1)
    gather_flush<IS_F32>(gp, cur, acc, NREL);
}

__global__ __launch_bounds__(256) void k_gather(
    const unsigned* __restrict__ packed,
    const unsigned short* __restrict__ normS,
    const void* __restrict__ h_raw,
    const int* __restrict__ A,
    __hip_bfloat16* __restrict__ g,
    const int* __restrict__ flag)
{
    if (*flag) gather_body<1>(packed, normS, h_raw, A, g);
    else       gather_body<0>(packed, normS, h_raw, A, g);
}

// ---------------------------------------------------------------------------
// K2 (MFMA GEMM): out[v][o] = relu( sum_k g[v][k] * Wf[k][o] ).
// 128-node tiles (391 blocks, ~1.5/CU), K chunked 4x256 in LDS (proven
// B-frag layout, stride 40). bf16 path: vectorized W staging (uint4 rows).
// ---------------------------------------------------------------------------
template<int IS_F32>
__device__ __forceinline__ void k2_body(
    const __hip_bfloat16* __restrict__ g,
    const void* __restrict__ w_raw,
    void* __restrict__ out,
    short* Wl)
{
    const int lane = threadIdx.x & 63;
    const int wave = threadIdx.x >> 6;
    const int n15  = lane & 15;
    const int quad = lane >> 4;
    const int nblk = blockIdx.x * 128;

    float4v acc[2][4];
#pragma unroll
    for (int ng = 0; ng < 2; ++ng)
#pragma unroll
        for (int t = 0; t < 4; ++t)
            acc[ng][t] = (float4v){0.f, 0.f, 0.f, 0.f};

    for (int kc = 0; kc < 4; ++kc) {
        __syncthreads();
        if (IS_F32) {
            for (int idx = threadIdx.x; idx < 16384; idx += 256) {
                int o = idx & 63, kl = idx >> 6;
                int s = kl >> 5, q = (kl >> 3) & 3, j = kl & 7;
                int k = kc * 256 + kl;
                float wv = ldx<IS_F32>(w_raw, (size_t)k * 64 + o);
                Wl[(s * 64 + o) * 40 + q * 8 + j] = (short)f2bfbits(wv);
            }
        } else {
            // bf16: copy rows vectorized, scatter 8 shorts per uint4
            for (int it = threadIdx.x; it < 2048; it += 256) {
                int kl = it >> 3, c8 = it & 7;
                const uint4 vv = *(const uint4*)((const unsigned short*)w_raw
                    + (size_t)(kc * 256 + kl) * 64 + c8 * 8);
                unsigned short el[8];
                __builtin_memcpy(el, &vv, 16);
                int s = kl >> 5, q = (kl >> 3) & 3, j = kl & 7;
                int boff = q * 8 + j;
#pragma unroll
                for (int m = 0; m < 8; ++m)
                    Wl[(s * 64 + c8 * 8 + m) * 40 + boff] = (short)el[m];
            }
        }
        __syncthreads();

#pragma unroll
        for (int ng = 0; ng < 2; ++ng) {
            const int node0 = nblk + ng * 64 + wave * 16;
            if (node0 >= N_NODES) continue;  // 50000 % 16 == 0

            const uint4* gp = (const uint4*)((const unsigned short*)g
                + (size_t)(node0 + n15) * KDIM + kc * 256 + quad * 8);
            short8 af[8];
#pragma unroll
            for (int s = 0; s < 8; ++s) {
                uint4 vv = gp[s * 4];   // s*32 shorts = 4 uint4
                __builtin_memcpy(&af[s], &vv, 16);
            }
#pragma unroll
            for (int s = 0; s < 8; ++s) {
#pragma unroll
                for (int t = 0; t < 4; ++t) {
                    const short8* bf = (const short8*)&Wl[(s * 64 + t * 16 + n15) * 40 + quad * 8];
                    acc[ng][t] = __builtin_amdgcn_mfma_f32_16x16x32_bf16(af[s], *bf, acc[ng][t], 0, 0, 0);
                }
            }
        }
    }

#pragma unroll
    for (int ng = 0; ng < 2; ++ng) {
        const int node0 = nblk + ng * 64 + wave * 16;
        if (node0 >= N_NODES) continue;
#pragma unroll
        for (int t = 0; t < 4; ++t) {
#pragma unroll
            for (int i = 0; i < 4; ++i) {
                int node = node0 + quad * 4 + i;
                float r = fmaxf(acc[ng][t][i], 0.f);
                size_t ob = (size_t)node * DIM + t * 16 + n15;
                if (IS_F32) ((float*)out)[ob] = r;
                else        ((unsigned short*)out)[ob] = f2bfbits(r);
            }
        }
    }
}

__global__ __launch_bounds__(256) void k2_mfma(
    const __hip_bfloat16* __restrict__ g,
    const void* __restrict__ w_raw,
    void* __restrict__ out,
    const int* __restrict__ flag)
{
    __shared__ short Wl[512 * 40];   // 40 KB
    if (*flag) k2_body<1>(g, w_raw, out, Wl);
    else       k2_body<0>(g, w_raw, out, Wl);
}

// ---------------------------------------------------------------------------
extern "C" void kernel_launch(void* const* d_in, const int* in_sizes, int n_in,
                              void* d_out, int out_size, void* d_ws, size_t ws_size,
                              hipStream_t stream)
{
    const void* h      = d_in[0];
    const void* weight = d_in[1];
    const void* norm   = d_in[2];
    const int* src = (const int*)d_in[3];
    const int* dst = (const int*)d_in[4];
    const int* rel = (const int*)d_in[5];

    // ws: flag(256) | A[50001] | base | tot | H | OT | packed u32[E]
    //     | normS u16[E] | g bf16[N*1024]  (R u64[E] aliases g; consumed by
    //     k_p2 before k_gather writes g — stream order)
    char* w = (char*)d_ws;
    int*   flag = (int*)w;                      w += 256;
    int*   A    = (int*)w;                      w += 200192;
    int*   base = (int*)w;                      w += 2048;
    int*   tot  = (int*)w;                      w += 2048;
    int*   H    = (int*)w;                      w += (size_t)P1_GRID * NBKT * 4;
    int*   OT   = (int*)w;                      w += (size_t)NBKT * P1_GRID * 4;
    unsigned* packed = (unsigned*)w;            w += (size_t)N_EDGES * 4;
    unsigned short* normS = (unsigned short*)w; w += (size_t)N_EDGES * 2;
    __hip_bfloat16* g = (__hip_bfloat16*)w;
    unsigned long long* R = (unsigned long long*)g;

    k_detect<<<1, 1024, 0, stream>>>((const float*)norm, flag);

    k_bhist<<<P1_GRID, 256, 0, stream>>>(dst, H);
    k_bscan1<<<NBKT, 256, 0, stream>>>(H, OT, tot);
    k_bscan2<<<1, 64, 0, stream>>>(tot, base);

    k_p1<<<P1_GRID, 256, 0, stream>>>(src, dst, rel, norm, base, OT, R, flag);
    k_p2<<<NBKT, 256, 0, stream>>>(base, R, packed, normS, A);

    k_gather<<<12500, 256, 0, stream>>>(packed, normS, h, A, g, flag);

    k2_mfma<<<(N_NODES + 127) / 128, 256, 0, stream>>>(g, weight, d_out, flag);
}